// Round 1
// baseline (111.493 us; speedup 1.0000x reference)
//
#include <hip/hip_runtime.h>
#include <math.h>

// Tacotron2 location-sensitive attention, fp32.
// B=64 T=2048 E=512 H=128 DL=1024 CC=32 K=31
// out = [context (B*E=32768), weights (B*T=131072)] fp32, concatenated.

#define BB 64
#define TT 2048
#define EE 512
#define HH 128
#define DLL 1024
#define CCC 32
#define KK 31

// ws layout (in floats)
#define WS_FW   0        // fw[128][32] (k=31 + 1 pad)     -> 4096 floats
#define WS_PL   4096     // pl[64][128]                    -> 8192 floats
#define WS_PART 12288    // partial[64][16][512]           -> 524288 floats
// total 536576 floats = 2.15 MB

// ---------------------------------------------------------------------------
// k0: blocks 0..63 compute pl[b][h] = sum_d lstm[b][d]*W_lstm[h][d]
//     block 64 computes fw[h][k] = sum_c W_loc[h][c]*conv_w[c][k]
// ---------------------------------------------------------------------------
__global__ __launch_bounds__(256) void k0_prep(const float* __restrict__ lstm,
                                               const float* __restrict__ Wl,
                                               const float* __restrict__ cw,
                                               const float* __restrict__ Wloc,
                                               float* __restrict__ ws) {
  const int blk = blockIdx.x;
  const int tid = threadIdx.x;
  if (blk < BB) {
    __shared__ __align__(16) float ls[DLL];
    ((float4*)ls)[tid] = ((const float4*)(lstm + blk * DLL))[tid];
    __syncthreads();
    const int wave = tid >> 6, lane = tid & 63;
    for (int hi = 0; hi < 32; ++hi) {
      const int h = hi * 4 + wave;
      const float4* wrow = (const float4*)(Wl + (size_t)h * DLL);
      float s = 0.f;
#pragma unroll
      for (int m = 0; m < 4; ++m) {
        float4 a = wrow[m * 64 + lane];
        float4 b = ((const float4*)ls)[m * 64 + lane];
        s += a.x * b.x + a.y * b.y + a.z * b.z + a.w * b.w;
      }
#pragma unroll
      for (int m = 1; m < 64; m <<= 1) s += __shfl_xor(s, m, 64);
      if (lane == 0) ws[WS_PL + blk * HH + h] = s;
    }
  } else {
    __shared__ __align__(16) float wl_s[HH * CCC];  // 4096
    __shared__ __align__(16) float cw_s[CCC * KK];  // 992
#pragma unroll
    for (int m = 0; m < 4; ++m)
      ((float4*)wl_s)[tid + 256 * m] = ((const float4*)Wloc)[tid + 256 * m];
    if (tid < 248) ((float4*)cw_s)[tid] = ((const float4*)cw)[tid];
    __syncthreads();
    const int h = tid >> 1;
    const int kbase = (tid & 1) * 16;
    const int kn = (tid & 1) ? 15 : 16;
    for (int kk = 0; kk < kn; ++kk) {
      const int k = kbase + kk;
      float s = 0.f;
#pragma unroll
      for (int c = 0; c < CCC; ++c) s += wl_s[h * CCC + c] * cw_s[c * KK + k];
      ws[WS_FW + h * 32 + k] = s;
    }
    if (tid & 1) ws[WS_FW + h * 32 + 31] = 0.f;  // pad
  }
}

// ---------------------------------------------------------------------------
// k1: energies[b][t] = sum_h We[h] * tanh(pl[b][h] + pe[b][t][h] + conv_h)
//     conv_h = sum_k fw[h][k] * aw[b][t+k-15] (zero pad)
// One wave processes 4 consecutive t; lane owns h in {2*lane, 2*lane+1}.
// ---------------------------------------------------------------------------
__global__ __launch_bounds__(256) void k1_energies(const float* __restrict__ pe,
                                                   const float* __restrict__ aw,
                                                   const float* __restrict__ We,
                                                   const float* __restrict__ ws,
                                                   float* __restrict__ Eout) {
  const int b = blockIdx.y;
  const int t0 = blockIdx.x * 256;
  const int tid = threadIdx.x;
  const int wave = tid >> 6, lane = tid & 63;

  __shared__ __align__(16) float aw_s[288];  // aw[t0-16 .. t0+271], zero-padded
  {
    int i = tid;
    int tg = t0 - 16 + i;
    aw_s[i] = (tg >= 0 && tg < TT) ? aw[b * TT + tg] : 0.f;
    if (tid < 32) {
      i = 256 + tid;
      tg = t0 - 16 + i;
      aw_s[i] = (tg >= 0 && tg < TT) ? aw[b * TT + tg] : 0.f;
    }
  }

  const int h0 = 2 * lane;
  float fw0[32], fw1[32];
  {
    const float4* f4 = (const float4*)(ws + WS_FW);
#pragma unroll
    for (int m = 0; m < 8; ++m) {
      float4 a = f4[h0 * 8 + m];
      fw0[4 * m + 0] = a.x; fw0[4 * m + 1] = a.y;
      fw0[4 * m + 2] = a.z; fw0[4 * m + 3] = a.w;
      float4 c = f4[h0 * 8 + 8 + m];
      fw1[4 * m + 0] = c.x; fw1[4 * m + 1] = c.y;
      fw1[4 * m + 2] = c.z; fw1[4 * m + 3] = c.w;
    }
  }
  const float2 plv = ((const float2*)(ws + WS_PL + b * HH))[lane];
  const float2 wev = ((const float2*)We)[lane];
  const float2* pe2 = (const float2*)(pe + (size_t)b * TT * HH);

  __syncthreads();

  for (int p = 0; p < 16; ++p) {
    const int tq = wave * 64 + p * 4;  // local quad start
    // pe loads first (hide latency under window unpack + FMAs)
    float2 pv[4];
#pragma unroll
    for (int j = 0; j < 4; ++j)
      pv[j] = pe2[(size_t)(t0 + tq + j) * 64 + lane];

    float w[36];
    const float4* a4 = (const float4*)&aw_s[tq];
#pragma unroll
    for (int m = 0; m < 9; ++m) {
      float4 v = a4[m];
      w[4 * m + 0] = v.x; w[4 * m + 1] = v.y;
      w[4 * m + 2] = v.z; w[4 * m + 3] = v.w;
    }

    float a0[4], a1[4];
#pragma unroll
    for (int j = 0; j < 4; ++j) {
      a0[j] = plv.x + pv[j].x;
      a1[j] = plv.y + pv[j].y;
    }
#pragma unroll
    for (int k = 0; k < 31; ++k) {
      const float f0 = fw0[k], f1 = fw1[k];
#pragma unroll
      for (int j = 0; j < 4; ++j) {
        a0[j] = fmaf(f0, w[1 + j + k], a0[j]);
        a1[j] = fmaf(f1, w[1 + j + k], a1[j]);
      }
    }
    float e[4];
#pragma unroll
    for (int j = 0; j < 4; ++j) {
      // tanh(x) = 1 - 2/(exp(2x)+1); exp->inf/0 gives exact +-1, safe
      const float th0 = 1.f - 2.f / (__expf(2.f * a0[j]) + 1.f);
      const float th1 = 1.f - 2.f / (__expf(2.f * a1[j]) + 1.f);
      e[j] = wev.x * th0 + wev.y * th1;
    }
#pragma unroll
    for (int m = 1; m < 64; m <<= 1) {
#pragma unroll
      for (int j = 0; j < 4; ++j) e[j] += __shfl_xor(e[j], m, 64);
    }
    if (lane == 0)
      *(float4*)&Eout[b * TT + t0 + tq] = make_float4(e[0], e[1], e[2], e[3]);
  }
}

// ---------------------------------------------------------------------------
// k2: in-place softmax over T per batch row (weights live in d_out)
// ---------------------------------------------------------------------------
__global__ __launch_bounds__(256) void k2_softmax(float* __restrict__ W) {
  const int b = blockIdx.x, tid = threadIdx.x;
  const int wave = tid >> 6, lane = tid & 63;
  float4* row4 = (float4*)(W + b * TT);
  float4 v0 = row4[tid * 2];
  float4 v1 = row4[tid * 2 + 1];
  float m = fmaxf(fmaxf(fmaxf(v0.x, v0.y), fmaxf(v0.z, v0.w)),
                  fmaxf(fmaxf(v1.x, v1.y), fmaxf(v1.z, v1.w)));
#pragma unroll
  for (int s = 1; s < 64; s <<= 1) m = fmaxf(m, __shfl_xor(m, s, 64));
  __shared__ float redm[4], reds[4];
  if (lane == 0) redm[wave] = m;
  __syncthreads();
  m = fmaxf(fmaxf(redm[0], redm[1]), fmaxf(redm[2], redm[3]));
  v0.x = __expf(v0.x - m); v0.y = __expf(v0.y - m);
  v0.z = __expf(v0.z - m); v0.w = __expf(v0.w - m);
  v1.x = __expf(v1.x - m); v1.y = __expf(v1.y - m);
  v1.z = __expf(v1.z - m); v1.w = __expf(v1.w - m);
  float s = v0.x + v0.y + v0.z + v0.w + v1.x + v1.y + v1.z + v1.w;
#pragma unroll
  for (int st = 1; st < 64; st <<= 1) s += __shfl_xor(s, st, 64);
  if (lane == 0) reds[wave] = s;
  __syncthreads();
  s = reds[0] + reds[1] + reds[2] + reds[3];
  const float inv = 1.f / s;
  v0.x *= inv; v0.y *= inv; v0.z *= inv; v0.w *= inv;
  v1.x *= inv; v1.y *= inv; v1.z *= inv; v1.w *= inv;
  row4[tid * 2] = v0;
  row4[tid * 2 + 1] = v1;
}

// ---------------------------------------------------------------------------
// k3: context partials: part[b][ts][e] = sum_{t in slice} w[b][t]*enc[b][t][e]
// ---------------------------------------------------------------------------
__global__ __launch_bounds__(256) void k3_ctx_part(const float* __restrict__ enc,
                                                   const float* __restrict__ Wt,
                                                   float* __restrict__ part) {
  const int ts = blockIdx.x;  // 0..15
  const int b = blockIdx.y;
  const int tid = threadIdx.x;
  const float2* enc2 = (const float2*)(enc + (size_t)b * TT * EE);
  const float* wrow = Wt + b * TT;
  const int tbase = ts * 128;
  float2 acc = {0.f, 0.f};
  for (int t = 0; t < 128; t += 2) {
    const float w0 = wrow[tbase + t];
    const float w1 = wrow[tbase + t + 1];
    const float2 v0 = enc2[(size_t)(tbase + t) * 256 + tid];
    const float2 v1 = enc2[(size_t)(tbase + t + 1) * 256 + tid];
    acc.x = fmaf(w0, v0.x, acc.x);
    acc.y = fmaf(w0, v0.y, acc.y);
    acc.x = fmaf(w1, v1.x, acc.x);
    acc.y = fmaf(w1, v1.y, acc.y);
  }
  ((float2*)part)[(b * 16 + ts) * 256 + tid] = acc;
}

__global__ __launch_bounds__(256) void k3_reduce(const float* __restrict__ part,
                                                 float* __restrict__ ctx) {
  const int idx = blockIdx.x * 256 + threadIdx.x;  // 0..16383 (float2 units)
  const int b = idx >> 8, e2 = idx & 255;
  const float2* p2 = (const float2*)part;
  float2 s = {0.f, 0.f};
#pragma unroll
  for (int ts = 0; ts < 16; ++ts) {
    const float2 v = p2[(b * 16 + ts) * 256 + e2];
    s.x += v.x;
    s.y += v.y;
  }
  ((float2*)ctx)[idx] = s;
}

// ---------------------------------------------------------------------------
extern "C" void kernel_launch(void* const* d_in, const int* in_sizes, int n_in,
                              void* d_out, int out_size, void* d_ws, size_t ws_size,
                              hipStream_t stream) {
  const float* enc  = (const float*)d_in[0];  // [B,T,E]
  const float* pe   = (const float*)d_in[1];  // [B,T,H]
  const float* lstm = (const float*)d_in[2];  // [B,1,DL]
  const float* awc  = (const float*)d_in[3];  // [B,T]
  const float* Wl   = (const float*)d_in[4];  // [H,DL]
  const float* cw   = (const float*)d_in[5];  // [CC,1,K]
  const float* Wloc = (const float*)d_in[6];  // [H,CC]
  const float* We   = (const float*)d_in[7];  // [1,H]

  float* out = (float*)d_out;
  float* ctx = out;            // [B,E]  = 32768 floats
  float* wts = out + BB * EE;  // [B,T]  = 131072 floats
  float* ws = (float*)d_ws;

  k0_prep<<<65, 256, 0, stream>>>(lstm, Wl, cw, Wloc, ws);
  k1_energies<<<dim3(TT / 256, BB), 256, 0, stream>>>(pe, awc, We, ws, wts);
  k2_softmax<<<BB, 256, 0, stream>>>(wts);
  k3_ctx_part<<<dim3(16, BB), 256, 0, stream>>>(enc, wts, ws + WS_PART);
  k3_reduce<<<BB, 256, 0, stream>>>(ws + WS_PART, ctx);
}

// Round 2
// 101.530 us; speedup vs baseline: 1.0981x; 1.0981x over previous
//
#include <hip/hip_runtime.h>
#include <math.h>

// Tacotron2 location-sensitive attention, fp32.
// B=64 T=2048 E=512 H=128 DL=1024 CC=32 K=31
// out = [context (B*E=32768), weights (B*T=131072)] fp32, concatenated.

#define BB 64
#define TT 2048
#define EE 512
#define HH 128
#define DLL 1024
#define CCC 32
#define KK 31

// ws layout (in floats)
#define WS_FW   0        // fw[128][32] (k=31 + 1 pad)     -> 4096 floats
#define WS_PL   4096     // pl[64][128]                    -> 8192 floats
#define WS_PART 12288    // partial[64][32][512]           -> 1048576 floats

// ---------------------------------------------------------------------------
// k0: blocks 0..2047: one wave per (b,h) dot  pl[b][h] = lstm[b]·W_lstm[h]
//     block 2048: fw[h][k] = sum_c W_loc[h][c]*conv_w[c][k]
// ---------------------------------------------------------------------------
__global__ __launch_bounds__(256) void k0_prep(const float* __restrict__ lstm,
                                               const float* __restrict__ Wl,
                                               const float* __restrict__ cw,
                                               const float* __restrict__ Wloc,
                                               float* __restrict__ ws) {
  const int blk = blockIdx.x;
  const int tid = threadIdx.x;
  if (blk < 2048) {
    const int wave = tid >> 6, lane = tid & 63;
    const int wg = blk * 4 + wave;      // 0..8191
    const int b = wg >> 7, h = wg & 127;
    const float4* wr = (const float4*)(Wl + (size_t)h * DLL);
    const float4* lr = (const float4*)(lstm + (size_t)b * DLL);
    float s = 0.f;
#pragma unroll
    for (int m = 0; m < 4; ++m) {
      float4 a = wr[m * 64 + lane];
      float4 c = lr[m * 64 + lane];
      s += a.x * c.x + a.y * c.y + a.z * c.z + a.w * c.w;
    }
#pragma unroll
    for (int m = 1; m < 64; m <<= 1) s += __shfl_xor(s, m, 64);
    if (lane == 0) ws[WS_PL + b * HH + h] = s;
  } else {
    __shared__ __align__(16) float wl_s[HH * CCC];  // 4096
    __shared__ __align__(16) float cw_s[CCC * KK];  // 992
#pragma unroll
    for (int m = 0; m < 4; ++m)
      ((float4*)wl_s)[tid + 256 * m] = ((const float4*)Wloc)[tid + 256 * m];
    if (tid < 248) ((float4*)cw_s)[tid] = ((const float4*)cw)[tid];
    __syncthreads();
    const int h = tid >> 1;
    const int kbase = (tid & 1) * 16;
    const int kn = (tid & 1) ? 15 : 16;
    for (int kk = 0; kk < kn; ++kk) {
      const int k = kbase + kk;
      float s = 0.f;
#pragma unroll
      for (int c = 0; c < CCC; ++c) s += wl_s[h * CCC + c] * cw_s[c * KK + k];
      ws[WS_FW + h * 32 + k] = s;
    }
    if (tid & 1) ws[WS_FW + h * 32 + 31] = 0.f;  // pad
  }
}

// ---------------------------------------------------------------------------
// k1: energies[b][t] = sum_h We[h] * tanh(pl[b][h] + pe[b][t][h] + conv_h)
//     conv_h = sum_k fw[h][k] * aw[b][t+k-15] (zero pad)
// t-chunk 128 per block (1024 blocks). One wave per 4 consecutive t;
// lane owns h in {2*lane, 2*lane+1}.
// ---------------------------------------------------------------------------
__global__ __launch_bounds__(256) void k1_energies(const float* __restrict__ pe,
                                                   const float* __restrict__ aw,
                                                   const float* __restrict__ We,
                                                   const float* __restrict__ ws,
                                                   float* __restrict__ Eout) {
  const int b = blockIdx.y;
  const int t0 = blockIdx.x * 128;
  const int tid = threadIdx.x;
  const int wave = tid >> 6, lane = tid & 63;

  __shared__ __align__(16) float aw_s[160];  // aw[t0-16 .. t0+143], zero-pad
  if (tid < 160) {
    const int tg = t0 - 16 + tid;
    aw_s[tid] = (tg >= 0 && tg < TT) ? aw[b * TT + tg] : 0.f;
  }

  const int h0 = 2 * lane;
  float fw0[32], fw1[32];
  {
    const float4* f4 = (const float4*)(ws + WS_FW);
#pragma unroll
    for (int m = 0; m < 8; ++m) {
      float4 a = f4[h0 * 8 + m];
      fw0[4 * m + 0] = a.x; fw0[4 * m + 1] = a.y;
      fw0[4 * m + 2] = a.z; fw0[4 * m + 3] = a.w;
      float4 c = f4[h0 * 8 + 8 + m];
      fw1[4 * m + 0] = c.x; fw1[4 * m + 1] = c.y;
      fw1[4 * m + 2] = c.z; fw1[4 * m + 3] = c.w;
    }
  }
  const float2 plv = ((const float2*)(ws + WS_PL + b * HH))[lane];
  const float2 wev = ((const float2*)We)[lane];
  const float2* pe2 = (const float2*)(pe + (size_t)b * TT * HH);

  __syncthreads();

  for (int p = 0; p < 8; ++p) {
    const int tq = wave * 32 + p * 4;  // local quad start
    float2 pv[4];
#pragma unroll
    for (int j = 0; j < 4; ++j)
      pv[j] = pe2[(size_t)(t0 + tq + j) * 64 + lane];

    float w[36];
    const float4* a4 = (const float4*)&aw_s[tq];
#pragma unroll
    for (int m = 0; m < 9; ++m) {
      float4 v = a4[m];
      w[4 * m + 0] = v.x; w[4 * m + 1] = v.y;
      w[4 * m + 2] = v.z; w[4 * m + 3] = v.w;
    }

    float a0[4], a1[4];
#pragma unroll
    for (int j = 0; j < 4; ++j) {
      a0[j] = plv.x + pv[j].x;
      a1[j] = plv.y + pv[j].y;
    }
#pragma unroll
    for (int k = 0; k < 31; ++k) {
      const float f0 = fw0[k], f1 = fw1[k];
#pragma unroll
      for (int j = 0; j < 4; ++j) {
        a0[j] = fmaf(f0, w[1 + j + k], a0[j]);
        a1[j] = fmaf(f1, w[1 + j + k], a1[j]);
      }
    }
    float e[4];
#pragma unroll
    for (int j = 0; j < 4; ++j) {
      const float th0 = 1.f - 2.f / (__expf(2.f * a0[j]) + 1.f);
      const float th1 = 1.f - 2.f / (__expf(2.f * a1[j]) + 1.f);
      e[j] = wev.x * th0 + wev.y * th1;
    }
#pragma unroll
    for (int m = 1; m < 64; m <<= 1) {
#pragma unroll
      for (int j = 0; j < 4; ++j) e[j] += __shfl_xor(e[j], m, 64);
    }
    if (lane == 0)
      *(float4*)&Eout[b * TT + t0 + tq] = make_float4(e[0], e[1], e[2], e[3]);
  }
}

// ---------------------------------------------------------------------------
// k2: in-place softmax over T per batch row (weights live in d_out)
// ---------------------------------------------------------------------------
__global__ __launch_bounds__(256) void k2_softmax(float* __restrict__ W) {
  const int b = blockIdx.x, tid = threadIdx.x;
  const int wave = tid >> 6, lane = tid & 63;
  float4* row4 = (float4*)(W + b * TT);
  float4 v0 = row4[tid * 2];
  float4 v1 = row4[tid * 2 + 1];
  float m = fmaxf(fmaxf(fmaxf(v0.x, v0.y), fmaxf(v0.z, v0.w)),
                  fmaxf(fmaxf(v1.x, v1.y), fmaxf(v1.z, v1.w)));
#pragma unroll
  for (int s = 1; s < 64; s <<= 1) m = fmaxf(m, __shfl_xor(m, s, 64));
  __shared__ float redm[4], reds[4];
  if (lane == 0) redm[wave] = m;
  __syncthreads();
  m = fmaxf(fmaxf(redm[0], redm[1]), fmaxf(redm[2], redm[3]));
  v0.x = __expf(v0.x - m); v0.y = __expf(v0.y - m);
  v0.z = __expf(v0.z - m); v0.w = __expf(v0.w - m);
  v1.x = __expf(v1.x - m); v1.y = __expf(v1.y - m);
  v1.z = __expf(v1.z - m); v1.w = __expf(v1.w - m);
  float s = v0.x + v0.y + v0.z + v0.w + v1.x + v1.y + v1.z + v1.w;
#pragma unroll
  for (int st = 1; st < 64; st <<= 1) s += __shfl_xor(s, st, 64);
  if (lane == 0) reds[wave] = s;
  __syncthreads();
  s = reds[0] + reds[1] + reds[2] + reds[3];
  const float inv = 1.f / s;
  v0.x *= inv; v0.y *= inv; v0.z *= inv; v0.w *= inv;
  v1.x *= inv; v1.y *= inv; v1.z *= inv; v1.w *= inv;
  row4[tid * 2] = v0;
  row4[tid * 2 + 1] = v1;
}

// ---------------------------------------------------------------------------
// k3: context partials: part[b][ts][e] = sum_{t in slice of 64} w[t]*enc[t][e]
// grid (32,64). float4 loads; weights staged in LDS.
// ---------------------------------------------------------------------------
__global__ __launch_bounds__(256) void k3_ctx_part(const float* __restrict__ enc,
                                                   const float* __restrict__ Wt,
                                                   float* __restrict__ part) {
  const int ts = blockIdx.x;  // 0..31
  const int b = blockIdx.y;
  const int tid = threadIdx.x;
  const int tbase = ts * 64;
  __shared__ float w_s[64];
  __shared__ __align__(16) float4 acc_s[128];
  if (tid < 64) w_s[tid] = Wt[b * TT + tbase + tid];
  __syncthreads();

  const float4* enc4 = (const float4*)(enc + (size_t)b * TT * EE);
  const int tp = tid >> 7;      // 0/1: t parity
  const int e4 = tid & 127;     // float4 column
  float4 acc = {0.f, 0.f, 0.f, 0.f};
#pragma unroll 4
  for (int t = tp; t < 64; t += 2) {
    const float w = w_s[t];
    const float4 v = enc4[(size_t)(tbase + t) * 128 + e4];
    acc.x = fmaf(w, v.x, acc.x);
    acc.y = fmaf(w, v.y, acc.y);
    acc.z = fmaf(w, v.z, acc.z);
    acc.w = fmaf(w, v.w, acc.w);
  }
  if (tp == 1) acc_s[e4] = acc;
  __syncthreads();
  if (tp == 0) {
    const float4 o = acc_s[e4];
    acc.x += o.x; acc.y += o.y; acc.z += o.z; acc.w += o.w;
    ((float4*)part)[(size_t)(b * 32 + ts) * 128 + e4] = acc;
  }
}

__global__ __launch_bounds__(256) void k3_reduce(const float* __restrict__ part,
                                                 float* __restrict__ ctx) {
  const int idx = blockIdx.x * 256 + threadIdx.x;  // 0..8191 (float4 units)
  const int b = idx >> 7, e4 = idx & 127;
  const float4* p4 = (const float4*)part;
  float4 s = {0.f, 0.f, 0.f, 0.f};
#pragma unroll
  for (int ts = 0; ts < 32; ++ts) {
    const float4 v = p4[(size_t)(b * 32 + ts) * 128 + e4];
    s.x += v.x; s.y += v.y; s.z += v.z; s.w += v.w;
  }
  ((float4*)ctx)[idx] = s;
}

// ---------------------------------------------------------------------------
extern "C" void kernel_launch(void* const* d_in, const int* in_sizes, int n_in,
                              void* d_out, int out_size, void* d_ws, size_t ws_size,
                              hipStream_t stream) {
  const float* enc  = (const float*)d_in[0];  // [B,T,E]
  const float* pe   = (const float*)d_in[1];  // [B,T,H]
  const float* lstm = (const float*)d_in[2];  // [B,1,DL]
  const float* awc  = (const float*)d_in[3];  // [B,T]
  const float* Wl   = (const float*)d_in[4];  // [H,DL]
  const float* cw   = (const float*)d_in[5];  // [CC,1,K]
  const float* Wloc = (const float*)d_in[6];  // [H,CC]
  const float* We   = (const float*)d_in[7];  // [1,H]

  float* out = (float*)d_out;
  float* ctx = out;            // [B,E]  = 32768 floats
  float* wts = out + BB * EE;  // [B,T]  = 131072 floats
  float* ws = (float*)d_ws;

  k0_prep<<<2049, 256, 0, stream>>>(lstm, Wl, cw, Wloc, ws);
  k1_energies<<<dim3(TT / 128, BB), 256, 0, stream>>>(pe, awc, We, ws, wts);
  k2_softmax<<<BB, 256, 0, stream>>>(wts);
  k3_ctx_part<<<dim3(32, BB), 256, 0, stream>>>(enc, wts, ws + WS_PART);
  k3_reduce<<<32, 256, 0, stream>>>(ws + WS_PART, ctx);
}